// Round 3
// baseline (216.397 us; speedup 1.0000x reference)
//
#include <hip/hip_runtime.h>
#include <math.h>

#define BATCH 8
#define SEQ 2048
#define DIM 128
#define SCALE 0.08838834764831845f  // 1/sqrt(128)
#define NEGINF (-1e30f)

typedef __attribute__((ext_vector_type(8))) short short8;
typedef __attribute__((ext_vector_type(4))) float floatx4;

union U8 { unsigned u[4]; short8 s; };

// pack two f32 -> bf16 pair (round-half-up): low16 = bf16(f0), high16 = bf16(f1)
// one v_add per value + one v_perm per pair
__device__ __forceinline__ unsigned pk_bf(float f0, float f1) {
    unsigned a = __float_as_uint(f0) + 0x8000u;
    unsigned b = __float_as_uint(f1) + 0x8000u;
    // qword = {S0=a (bytes 4-7), S1=b (bytes 0-3)}; sel 0x03020706:
    // result bytes {a2,a3,b2,b3} -> low16 = a>>16, high16 = b>>16
    return __builtin_amdgcn_perm(a, b, 0x03020706u);
}

// ---------------- vmean: mean of all SEQ V-rows per batch ----------------
__global__ __launch_bounds__(256) void vmean_partial(const float* __restrict__ v,
                                                     float* __restrict__ part) {
    int blk = blockIdx.x;            // 64 blocks: b*8 + oct
    int b = blk >> 3, oct = blk & 7;
    int t = threadIdx.x;
    int d4 = t & 31, rg = t >> 5;
    const float4* vb = (const float4*)(v + (size_t)b * SEQ * DIM);
    float4 acc = make_float4(0.f, 0.f, 0.f, 0.f);
    int base = oct * 256 + rg * 32;
    #pragma unroll 8
    for (int i = 0; i < 32; ++i) {
        float4 x = vb[(size_t)(base + i) * 32 + d4];
        acc.x += x.x; acc.y += x.y; acc.z += x.z; acc.w += x.w;
    }
    __shared__ float4 red[8][32];
    red[rg][d4] = acc;
    __syncthreads();
    if (t < 32) {
        float4 s = red[0][t];
        #pragma unroll
        for (int r = 1; r < 8; ++r) {
            float4 x = red[r][t];
            s.x += x.x; s.y += x.y; s.z += x.z; s.w += x.w;
        }
        ((float4*)part)[(size_t)blk * 32 + t] = s;
    }
}

__global__ __launch_bounds__(128) void vmean_combine(const float* __restrict__ part,
                                                     float* __restrict__ vmean) {
    int b = blockIdx.x, t = threadIdx.x;
    float s = 0.f;
    #pragma unroll
    for (int o = 0; o < 8; ++o) s += part[((size_t)b * 8 + o) * DIM + t];
    vmean[b * DIM + t] = s * (1.0f / SEQ);
}

// ---------------- barrier-free per-wave MFMA flash attention ----------------
// Block = 512 threads = 8 waves = 2 q-tiles (16 rows) x 4 key-slices.
// Grid = 8 * 64 = 512 blocks (2/CU); blk&7 = batch. No barriers in K-loop.
// Orientation: S^T = K.Q^T (C: row=key, col=qrow), O^T accumulated as
// C frags (row=d_local, col=qrow) -> m,l,alpha are per-lane scalars.
#define PSTR 40   // P tile row stride in bf16 units (80 B, 16B-aligned rows)

__global__ __launch_bounds__(512, 4) void attn_flash(const float* __restrict__ q,
                                                     const float* __restrict__ k,
                                                     const float* __restrict__ v,
                                                     const int* __restrict__ lens,
                                                     const float* __restrict__ vmean,
                                                     float* __restrict__ out) {
    __shared__ unsigned short sP[8 * 16 * PSTR];   // 10240 B: per-wave P tiles
    __shared__ float sC[2][3][16][132];            // 50688 B: kslice O partials
    __shared__ float sS[2][4][16][2];              //  1024 B: (m,l) per slice

    int blk = blockIdx.x;
    int b = blk & 7;
    int g = blk >> 3;                // 0..63
    int q0 = g * 32;
    int len = lens[b];
    int t = threadIdx.x;
    int lane = t & 63;
    int wave = t >> 6;               // 0..7
    int qt = wave & 1;               // q-tile within block
    int ks = wave >> 1;              // key-slice 0..3
    int l16 = lane & 15;
    int quad = lane >> 4;
    const int bo = b * SEQ * DIM;    // fits int (max 2M)

    int rowbase = q0 + qt * 16;
    bool active = q0 < len;

    int slice = (len + 3) >> 2;
    int kbeg = ks * slice;
    int kend = min(kbeg + slice, len);

    floatx4 O[8];                    // O^T frags: d = dt*16 + quad*4 + r, qrow = l16
    #pragma unroll
    for (int dt = 0; dt < 8; ++dt) O[dt] = (floatx4){0.f, 0.f, 0.f, 0.f};
    float m = NEGINF, l = 0.f;

    unsigned short* sPw = &sP[wave * 16 * PSTR];

    if (active && kbeg < kend) {
        // ---- Q B-frags (persist): B[k=d][n=qrow]: Q[rowbase+l16][ds*32+quad*8+jj]
        short8 Qf[4];
        {
            const float* qp = q + bo + (rowbase + l16) * DIM + quad * 8;
            #pragma unroll
            for (int ds = 0; ds < 4; ++ds) {
                float4 x0 = *(const float4*)(qp + ds * 32);
                float4 x1 = *(const float4*)(qp + ds * 32 + 4);
                U8 f;
                f.u[0] = pk_bf(x0.x, x0.y); f.u[1] = pk_bf(x0.z, x0.w);
                f.u[2] = pk_bf(x1.x, x1.y); f.u[3] = pk_bf(x1.z, x1.w);
                Qf[ds] = f.s;
            }
        }

        for (int kb = kbeg; kb < kend; kb += 32) {
            // ---- QK^T: two 16-key ntiles, A=K direct from global ----
            int kr0 = kb + l16;      kr0 = kr0 < SEQ ? kr0 : SEQ - 1;
            int kr1 = kb + 16 + l16; kr1 = kr1 < SEQ ? kr1 : SEQ - 1;
            const float* kp0 = k + bo + kr0 * DIM + quad * 8;
            const float* kp1 = k + bo + kr1 * DIM + quad * 8;
            floatx4 S0 = (floatx4){0.f, 0.f, 0.f, 0.f};
            floatx4 S1 = (floatx4){0.f, 0.f, 0.f, 0.f};
            #pragma unroll
            for (int ds = 0; ds < 4; ++ds) {
                float4 a0 = *(const float4*)(kp0 + ds * 32);
                float4 a1 = *(const float4*)(kp0 + ds * 32 + 4);
                U8 f;
                f.u[0] = pk_bf(a0.x, a0.y); f.u[1] = pk_bf(a0.z, a0.w);
                f.u[2] = pk_bf(a1.x, a1.y); f.u[3] = pk_bf(a1.z, a1.w);
                S0 = __builtin_amdgcn_mfma_f32_16x16x32_bf16(f.s, Qf[ds], S0, 0, 0, 0);
            }
            #pragma unroll
            for (int ds = 0; ds < 4; ++ds) {
                float4 a0 = *(const float4*)(kp1 + ds * 32);
                float4 a1 = *(const float4*)(kp1 + ds * 32 + 4);
                U8 f;
                f.u[0] = pk_bf(a0.x, a0.y); f.u[1] = pk_bf(a0.z, a0.w);
                f.u[2] = pk_bf(a1.x, a1.y); f.u[3] = pk_bf(a1.z, a1.w);
                S1 = __builtin_amdgcn_mfma_f32_16x16x32_bf16(f.s, Qf[ds], S1, 0, 0, 0);
            }

            // ---- online softmax: stats per qrow = per lane (reduce across quads)
            int kl0 = kb + quad * 4;
            int kl1 = kb + 16 + quad * 4;
            float s0v[4], s1v[4];
            float mt = m;
            #pragma unroll
            for (int r = 0; r < 4; ++r) {
                s0v[r] = (kl0 + r < kend) ? S0[r] * SCALE : NEGINF;
                s1v[r] = (kl1 + r < kend) ? S1[r] * SCALE : NEGINF;
                mt = fmaxf(mt, fmaxf(s0v[r], s1v[r]));
            }
            mt = fmaxf(mt, __shfl_xor(mt, 16));
            mt = fmaxf(mt, __shfl_xor(mt, 32));
            float alpha = __expf(m - mt);
            m = mt;
            float p0[4], p1[4], ps = 0.f;
            #pragma unroll
            for (int r = 0; r < 4; ++r) {
                p0[r] = __expf(s0v[r] - mt);   // masked -> exp(-1e30) = 0
                p1[r] = __expf(s1v[r] - mt);
                ps += p0[r] + p1[r];
            }
            ps += __shfl_xor(ps, 16);
            ps += __shfl_xor(ps, 32);
            l = l * alpha + ps;
            #pragma unroll
            for (int dt = 0; dt < 8; ++dt) {
                #pragma unroll
                for (int r = 0; r < 4; ++r) O[dt][r] *= alpha;
            }

            // ---- P^T -> LDS [qrow][key] (wave-local, one b64 write per ntile)
            {
                uint2 w0, w1;
                w0.x = pk_bf(p0[0], p0[1]); w0.y = pk_bf(p0[2], p0[3]);
                w1.x = pk_bf(p1[0], p1[1]); w1.y = pk_bf(p1[2], p1[3]);
                *(uint2*)&sPw[l16 * PSTR + quad * 4]      = w0;
                *(uint2*)&sPw[l16 * PSTR + 16 + quad * 4] = w1;
            }
            // B-frag read: P[qrow=l16][key=quad*8+jj], contiguous 16B
            short8 Pf = *(const short8*)&sPw[l16 * PSTR + quad * 8];

            // ---- PV: A = V^T direct from global: V[kb+quad*8+jj][dt*16+l16]
            int vro[8];
            #pragma unroll
            for (int jj = 0; jj < 8; ++jj) {
                int kk = kb + quad * 8 + jj;
                kk = kk < SEQ ? kk : SEQ - 1;
                vro[jj] = kk * DIM;
            }
            const float* vb = v + bo + l16;
            #pragma unroll
            for (int dt = 0; dt < 8; ++dt) {
                int c = dt * 16;
                float x0 = vb[vro[0] + c], x1 = vb[vro[1] + c];
                float x2 = vb[vro[2] + c], x3 = vb[vro[3] + c];
                float x4 = vb[vro[4] + c], x5 = vb[vro[5] + c];
                float x6 = vb[vro[6] + c], x7 = vb[vro[7] + c];
                U8 f;
                f.u[0] = pk_bf(x0, x1); f.u[1] = pk_bf(x2, x3);
                f.u[2] = pk_bf(x4, x5); f.u[3] = pk_bf(x6, x7);
                O[dt] = __builtin_amdgcn_mfma_f32_16x16x32_bf16(f.s, Pf, O[dt], 0, 0, 0);
            }
        }
    }

    // ---- cross-slice combine (once per block) ----
    if (active && ks > 0) {
        if (quad == 0) { sS[qt][ks][l16][0] = m; sS[qt][ks][l16][1] = l; }
        #pragma unroll
        for (int dt = 0; dt < 8; ++dt)
            *(floatx4*)&sC[qt][ks - 1][l16][dt * 16 + quad * 4] = O[dt];
    }
    __syncthreads();

    if (ks == 0) {
        const float* vm = vmean + b * DIM;
        float* ob = out + bo + (rowbase + l16) * DIM;
        if (active) {
            float mw[3], lw[3];
            float mstar = m;
            #pragma unroll
            for (int w = 0; w < 3; ++w) {
                mw[w] = sS[qt][w + 1][l16][0];
                lw[w] = sS[qt][w + 1][l16][1];
                mstar = fmaxf(mstar, mw[w]);
            }
            float s0 = __expf(m - mstar);
            float sw[3];
            float lstar = s0 * l;
            #pragma unroll
            for (int w = 0; w < 3; ++w) {
                sw[w] = __expf(mw[w] - mstar);
                lstar += sw[w] * lw[w];
            }
            float inv = 1.f / lstar;
            bool rowvalid = (rowbase + l16) < len;
            #pragma unroll
            for (int dt = 0; dt < 8; ++dt) {
                floatx4 acc = O[dt];
                #pragma unroll
                for (int r = 0; r < 4; ++r) acc[r] *= s0;
                #pragma unroll
                for (int w = 0; w < 3; ++w) {
                    floatx4 ow = *(const floatx4*)&sC[qt][w][l16][dt * 16 + quad * 4];
                    #pragma unroll
                    for (int r = 0; r < 4; ++r) acc[r] += sw[w] * ow[r];
                }
                float4 res;
                if (rowvalid) {
                    res = make_float4(acc[0] * inv, acc[1] * inv, acc[2] * inv, acc[3] * inv);
                } else {
                    res = *(const float4*)(vm + dt * 16 + quad * 4);
                }
                *(float4*)(ob + dt * 16 + quad * 4) = res;
            }
        } else {
            #pragma unroll
            for (int dt = 0; dt < 8; ++dt)
                *(float4*)(ob + dt * 16 + quad * 4) =
                    *(const float4*)(vm + dt * 16 + quad * 4);
        }
    }
}

extern "C" void kernel_launch(void* const* d_in, const int* in_sizes, int n_in,
                              void* d_out, int out_size, void* d_ws, size_t ws_size,
                              hipStream_t stream) {
    const float* q = (const float*)d_in[0];
    const float* k = (const float*)d_in[1];
    const float* v = (const float*)d_in[2];
    const int* lens = (const int*)d_in[3];
    float* out = (float*)d_out;

    float* part = (float*)d_ws;                 // 64*128 floats
    float* vmean = part + 64 * DIM;             // 8*128 floats

    vmean_partial<<<dim3(64), dim3(256), 0, stream>>>(v, part);
    vmean_combine<<<dim3(8), dim3(128), 0, stream>>>(part, vmean);
    attn_flash<<<dim3(512), dim3(512), 0, stream>>>(q, k, v, lens, vmean, out);
}

// Round 4
// 197.322 us; speedup vs baseline: 1.0967x; 1.0967x over previous
//
#include <hip/hip_runtime.h>
#include <math.h>

#define BATCH 8
#define SEQ 2048
#define DIM 128
#define SCALE 0.08838834764831845f  // 1/sqrt(128)
#define NEGINF (-1e30f)
#define INVSEQ (1.0f / 2048.0f)

typedef __attribute__((ext_vector_type(8))) short short8;
typedef __attribute__((ext_vector_type(4))) float floatx4;

union U8 { unsigned u[4]; short8 s; };

// pack two f32 -> bf16 pair (round-half-up): low16 = bf16(f0), high16 = bf16(f1)
__device__ __forceinline__ unsigned pk_bf(float f0, float f1) {
    unsigned a = __float_as_uint(f0) + 0x8000u;
    unsigned b = __float_as_uint(f1) + 0x8000u;
    return __builtin_amdgcn_perm(a, b, 0x03020706u);
}
__device__ __forceinline__ unsigned short bf1(float f) {
    return (unsigned short)((__float_as_uint(f) + 0x8000u) >> 16);
}

// =================== pre-pass: K*SCALE -> bf16 rowmajor; V -> bf16 [b][d][s]; vsum ===================
__global__ __launch_bounds__(256) void conv_kernel(const float* __restrict__ k,
                                                   const float* __restrict__ v,
                                                   unsigned short* __restrict__ kbf,
                                                   unsigned short* __restrict__ vt,
                                                   float* __restrict__ vsum) {
    __shared__ unsigned short sT[DIM * 136];   // transpose tile, stride 136 (272B rows, 16B aligned)
    int blk = blockIdx.x, t = threadIdx.x;
    if (blk < 128) {
        // K convert: grid-stride over 524288 float4
        const float4* k4 = (const float4*)k;
        uint2* kb2 = (uint2*)kbf;
        int base = blk * 256 + t;
        #pragma unroll
        for (int it = 0; it < 16; ++it) {
            int i = base + it * 32768;
            float4 x = k4[i];
            uint2 p;
            p.x = pk_bf(x.x * SCALE, x.y * SCALE);
            p.y = pk_bf(x.z * SCALE, x.w * SCALE);
            kb2[i] = p;
        }
    } else {
        // V transpose: block = (b, 128-key tile)
        int blk2 = blk - 128;
        int b = blk2 >> 4, k0 = (blk2 & 15) * 128;
        int d4 = t & 31;
        const float4* v4 = (const float4*)(v + ((size_t)b * SEQ + k0) * DIM);
        float4 acc = make_float4(0.f, 0.f, 0.f, 0.f);
        #pragma unroll
        for (int it = 0; it < 16; ++it) {
            int key = it * 8 + (t >> 5);
            float4 x = v4[key * 32 + d4];
            acc.x += x.x; acc.y += x.y; acc.z += x.z; acc.w += x.w;
            sT[(d4 * 4 + 0) * 136 + key] = bf1(x.x);
            sT[(d4 * 4 + 1) * 136 + key] = bf1(x.y);
            sT[(d4 * 4 + 2) * 136 + key] = bf1(x.z);
            sT[(d4 * 4 + 3) * 136 + key] = bf1(x.w);
        }
        atomicAdd(&vsum[b * DIM + d4 * 4 + 0], acc.x);
        atomicAdd(&vsum[b * DIM + d4 * 4 + 1], acc.y);
        atomicAdd(&vsum[b * DIM + d4 * 4 + 2], acc.z);
        atomicAdd(&vsum[b * DIM + d4 * 4 + 3], acc.w);
        __syncthreads();
        unsigned short* vtb = vt + (size_t)b * DIM * SEQ;
        #pragma unroll
        for (int it = 0; it < 8; ++it) {
            int d = it * 16 + (t >> 4);
            int k16 = t & 15;
            short8 row = *(const short8*)&sT[d * 136 + k16 * 8];
            *(short8*)(vtb + (size_t)d * SEQ + k0 + k16 * 8) = row;
        }
    }
}

// =================== MFMA flash attention (pre-converted bf16 K,V^T) ===================
// Block = 256 thr = 4 waves = 1 q-tile (16 rows) x 4 key-slices. Grid = 8*128 blocks.
// S^T = Kbf . Qbf^T (scale folded into K); O^T = V^T . P^T. No packing in K-loop.
#define PSTR 40

__global__ __launch_bounds__(256, 4) void attn_mx(const float* __restrict__ q,
                                                  const unsigned short* __restrict__ kbf,
                                                  const unsigned short* __restrict__ vt,
                                                  const int* __restrict__ lens,
                                                  const float* __restrict__ vsum,
                                                  float* __restrict__ out) {
    __shared__ unsigned short sP[4 * 16 * PSTR];   //  5120 B
    __shared__ float sC[3][16][132];               // 25344 B
    __shared__ float sS[4][16][2];                 //   512 B

    int blk = blockIdx.x;
    int b = blk & 7;
    int q0 = (blk >> 3) * 16;
    int len = lens[b];
    int t = threadIdx.x;
    int lane = t & 63;
    int ks = t >> 6;                 // key-slice 0..3
    int l16 = lane & 15;
    int quad = lane >> 4;
    const int bo = b * SEQ * DIM;

    if (q0 >= len) {                 // block-uniform: whole tile -> vmean rows
        int row = t >> 4;
        int c0 = (t & 15) * 8;
        float4 a = *(const float4*)&vsum[b * DIM + c0];
        float4 c = *(const float4*)&vsum[b * DIM + c0 + 4];
        a.x *= INVSEQ; a.y *= INVSEQ; a.z *= INVSEQ; a.w *= INVSEQ;
        c.x *= INVSEQ; c.y *= INVSEQ; c.z *= INVSEQ; c.w *= INVSEQ;
        float* op = out + bo + (q0 + row) * DIM + c0;
        *(float4*)op = a;
        *(float4*)(op + 4) = c;
        return;
    }

    // slice aligned to 32 so V^T dwordx4 reads stay 16B-aligned
    int slice = ((len + 127) >> 7) << 5;
    int kbeg = ks * slice;
    int kend = min(kbeg + slice, len);

    floatx4 O[8];
    #pragma unroll
    for (int dt = 0; dt < 8; ++dt) O[dt] = (floatx4){0.f, 0.f, 0.f, 0.f};
    float m = NEGINF, l = 0.f;
    unsigned short* sPw = &sP[ks * 16 * PSTR];

    // Q B-frags: B[k=d][n=qrow=l16], d = ds*32 + quad*8 + jj
    short8 Qf[4];
    {
        const float* qp = q + bo + (q0 + l16) * DIM + quad * 8;
        #pragma unroll
        for (int ds = 0; ds < 4; ++ds) {
            float4 x0 = *(const float4*)(qp + ds * 32);
            float4 x1 = *(const float4*)(qp + ds * 32 + 4);
            U8 f;
            f.u[0] = pk_bf(x0.x, x0.y); f.u[1] = pk_bf(x0.z, x0.w);
            f.u[2] = pk_bf(x1.x, x1.y); f.u[3] = pk_bf(x1.z, x1.w);
            Qf[ds] = f.s;
        }
    }

    const unsigned short* kB = kbf + (size_t)b * SEQ * DIM;
    const unsigned short* vB = vt + (size_t)b * DIM * SEQ;

    for (int kb = kbeg; kb < kend; kb += 32) {
        // ---- K A-frags direct from global (already bf16, scaled) ----
        int kr0 = min(kb + l16, SEQ - 1);
        int kr1 = min(kb + 16 + l16, SEQ - 1);
        const unsigned short* kp0 = kB + kr0 * DIM + quad * 8;
        const unsigned short* kp1 = kB + kr1 * DIM + quad * 8;
        floatx4 S0 = (floatx4){0.f, 0.f, 0.f, 0.f};
        floatx4 S1 = (floatx4){0.f, 0.f, 0.f, 0.f};
        #pragma unroll
        for (int ds = 0; ds < 4; ++ds)
            S0 = __builtin_amdgcn_mfma_f32_16x16x32_bf16(*(const short8*)(kp0 + ds * 32), Qf[ds], S0, 0, 0, 0);
        #pragma unroll
        for (int ds = 0; ds < 4; ++ds)
            S1 = __builtin_amdgcn_mfma_f32_16x16x32_bf16(*(const short8*)(kp1 + ds * 32), Qf[ds], S1, 0, 0, 0);

        // ---- issue V^T A-frag loads now; latency hides behind softmax ----
        int kv = min(kb + quad * 8, SEQ - 8);
        const unsigned short* vp = vB + kv;
        short8 Vf[8];
        #pragma unroll
        for (int dt = 0; dt < 8; ++dt)
            Vf[dt] = *(const short8*)(vp + (size_t)(dt * 16 + l16) * SEQ);

        // ---- online softmax (stats per qrow = per lane; reduce across quads) ----
        int kl0 = kb + quad * 4;
        int kl1 = kl0 + 16;
        float s0v[4], s1v[4];
        float mt = m;
        #pragma unroll
        for (int r = 0; r < 4; ++r) {
            s0v[r] = (kl0 + r < kend) ? S0[r] : NEGINF;   // scale already in K
            s1v[r] = (kl1 + r < kend) ? S1[r] : NEGINF;
            mt = fmaxf(mt, fmaxf(s0v[r], s1v[r]));
        }
        mt = fmaxf(mt, __shfl_xor(mt, 16));
        mt = fmaxf(mt, __shfl_xor(mt, 32));
        float alpha = __expf(m - mt);
        m = mt;
        float p0[4], p1[4], ps = 0.f;
        #pragma unroll
        for (int r = 0; r < 4; ++r) {
            p0[r] = __expf(s0v[r] - mt);
            p1[r] = __expf(s1v[r] - mt);
            ps += p0[r] + p1[r];
        }
        ps += __shfl_xor(ps, 16);
        ps += __shfl_xor(ps, 32);
        l = l * alpha + ps;
        #pragma unroll
        for (int dt = 0; dt < 8; ++dt) {
            #pragma unroll
            for (int r = 0; r < 4; ++r) O[dt][r] *= alpha;
        }

        // ---- P^T C->B layout via wave-local LDS round trip ----
        {
            uint2 w0, w1;
            w0.x = pk_bf(p0[0], p0[1]); w0.y = pk_bf(p0[2], p0[3]);
            w1.x = pk_bf(p1[0], p1[1]); w1.y = pk_bf(p1[2], p1[3]);
            *(uint2*)&sPw[l16 * PSTR + quad * 4]      = w0;
            *(uint2*)&sPw[l16 * PSTR + 16 + quad * 4] = w1;
        }
        short8 Pf = *(const short8*)&sPw[l16 * PSTR + quad * 8];

        // ---- PV ----
        #pragma unroll
        for (int dt = 0; dt < 8; ++dt)
            O[dt] = __builtin_amdgcn_mfma_f32_16x16x32_bf16(Vf[dt], Pf, O[dt], 0, 0, 0);
    }

    // ---- cross-slice combine ----
    if (ks > 0) {
        if (quad == 0) { sS[ks][l16][0] = m; sS[ks][l16][1] = l; }
        #pragma unroll
        for (int dt = 0; dt < 8; ++dt)
            *(floatx4*)&sC[ks - 1][l16][dt * 16 + quad * 4] = O[dt];
    }
    __syncthreads();

    if (ks == 0) {
        float mw[3], lw[3];
        float mstar = m;
        #pragma unroll
        for (int w = 0; w < 3; ++w) {
            mw[w] = sS[w + 1][l16][0];
            lw[w] = sS[w + 1][l16][1];
            mstar = fmaxf(mstar, mw[w]);
        }
        float s0 = __expf(m - mstar);
        float sw[3];
        float lstar = s0 * l;
        #pragma unroll
        for (int w = 0; w < 3; ++w) {
            sw[w] = __expf(mw[w] - mstar);
            lstar += sw[w] * lw[w];
        }
        float inv = 1.f / lstar;
        bool rowvalid = (q0 + l16) < len;
        float* ob = out + bo + (q0 + l16) * DIM;
        const float* vm = vsum + b * DIM;
        #pragma unroll
        for (int dt = 0; dt < 8; ++dt) {
            floatx4 acc = O[dt];
            #pragma unroll
            for (int r = 0; r < 4; ++r) acc[r] *= s0;
            #pragma unroll
            for (int w = 0; w < 3; ++w) {
                floatx4 ow = *(const floatx4*)&sC[w][l16][dt * 16 + quad * 4];
                #pragma unroll
                for (int r = 0; r < 4; ++r) acc[r] += sw[w] * ow[r];
            }
            float4 res;
            if (rowvalid) {
                res = make_float4(acc[0] * inv, acc[1] * inv, acc[2] * inv, acc[3] * inv);
            } else {
                const float4 vmv = *(const float4*)(vm + dt * 16 + quad * 4);
                res = make_float4(vmv.x * INVSEQ, vmv.y * INVSEQ, vmv.z * INVSEQ, vmv.w * INVSEQ);
            }
            *(float4*)(ob + dt * 16 + quad * 4) = res;
        }
    }
}

// =================== fallback path (R3, used only if ws too small) ===================
__global__ __launch_bounds__(256) void vmean_partial(const float* __restrict__ v,
                                                     float* __restrict__ part) {
    int blk = blockIdx.x;
    int b = blk >> 3, oct = blk & 7;
    int t = threadIdx.x;
    int d4 = t & 31, rg = t >> 5;
    const float4* vb = (const float4*)(v + (size_t)b * SEQ * DIM);
    float4 acc = make_float4(0.f, 0.f, 0.f, 0.f);
    int base = oct * 256 + rg * 32;
    #pragma unroll 8
    for (int i = 0; i < 32; ++i) {
        float4 x = vb[(size_t)(base + i) * 32 + d4];
        acc.x += x.x; acc.y += x.y; acc.z += x.z; acc.w += x.w;
    }
    __shared__ float4 red[8][32];
    red[rg][d4] = acc;
    __syncthreads();
    if (t < 32) {
        float4 s = red[0][t];
        #pragma unroll
        for (int r = 1; r < 8; ++r) {
            float4 x = red[r][t];
            s.x += x.x; s.y += x.y; s.z += x.z; s.w += x.w;
        }
        ((float4*)part)[(size_t)blk * 32 + t] = s;
    }
}

__global__ __launch_bounds__(128) void vmean_combine(const float* __restrict__ part,
                                                     float* __restrict__ vmean) {
    int b = blockIdx.x, t = threadIdx.x;
    float s = 0.f;
    #pragma unroll
    for (int o = 0; o < 8; ++o) s += part[((size_t)b * 8 + o) * DIM + t];
    vmean[b * DIM + t] = s * (1.0f / SEQ);
}

__global__ __launch_bounds__(512, 4) void attn_flash(const float* __restrict__ q,
                                                     const float* __restrict__ k,
                                                     const float* __restrict__ v,
                                                     const int* __restrict__ lens,
                                                     const float* __restrict__ vmean,
                                                     float* __restrict__ out) {
    __shared__ unsigned short sPf[8 * 16 * PSTR];
    __shared__ float sC[2][3][16][132];
    __shared__ float sS[2][4][16][2];

    int blk = blockIdx.x;
    int b = blk & 7;
    int g = blk >> 3;
    int q0 = g * 32;
    int len = lens[b];
    int t = threadIdx.x;
    int lane = t & 63;
    int wave = t >> 6;
    int qt = wave & 1;
    int ks = wave >> 1;
    int l16 = lane & 15;
    int quad = lane >> 4;
    const int bo = b * SEQ * DIM;

    int rowbase = q0 + qt * 16;
    bool active = q0 < len;

    int slice = (len + 3) >> 2;
    int kbeg = ks * slice;
    int kend = min(kbeg + slice, len);

    floatx4 O[8];
    #pragma unroll
    for (int dt = 0; dt < 8; ++dt) O[dt] = (floatx4){0.f, 0.f, 0.f, 0.f};
    float m = NEGINF, l = 0.f;
    unsigned short* sPw = &sPf[wave * 16 * PSTR];

    if (active && kbeg < kend) {
        short8 Qf[4];
        {
            const float* qp = q + bo + (rowbase + l16) * DIM + quad * 8;
            #pragma unroll
            for (int ds = 0; ds < 4; ++ds) {
                float4 x0 = *(const float4*)(qp + ds * 32);
                float4 x1 = *(const float4*)(qp + ds * 32 + 4);
                U8 f;
                f.u[0] = pk_bf(x0.x, x0.y); f.u[1] = pk_bf(x0.z, x0.w);
                f.u[2] = pk_bf(x1.x, x1.y); f.u[3] = pk_bf(x1.z, x1.w);
                Qf[ds] = f.s;
            }
        }
        for (int kb = kbeg; kb < kend; kb += 32) {
            int kr0 = kb + l16;      kr0 = kr0 < SEQ ? kr0 : SEQ - 1;
            int kr1 = kb + 16 + l16; kr1 = kr1 < SEQ ? kr1 : SEQ - 1;
            const float* kp0 = k + bo + kr0 * DIM + quad * 8;
            const float* kp1 = k + bo + kr1 * DIM + quad * 8;
            floatx4 S0 = (floatx4){0.f, 0.f, 0.f, 0.f};
            floatx4 S1 = (floatx4){0.f, 0.f, 0.f, 0.f};
            #pragma unroll
            for (int ds = 0; ds < 4; ++ds) {
                float4 a0 = *(const float4*)(kp0 + ds * 32);
                float4 a1 = *(const float4*)(kp0 + ds * 32 + 4);
                U8 f;
                f.u[0] = pk_bf(a0.x, a0.y); f.u[1] = pk_bf(a0.z, a0.w);
                f.u[2] = pk_bf(a1.x, a1.y); f.u[3] = pk_bf(a1.z, a1.w);
                S0 = __builtin_amdgcn_mfma_f32_16x16x32_bf16(f.s, Qf[ds], S0, 0, 0, 0);
            }
            #pragma unroll
            for (int ds = 0; ds < 4; ++ds) {
                float4 a0 = *(const float4*)(kp1 + ds * 32);
                float4 a1 = *(const float4*)(kp1 + ds * 32 + 4);
                U8 f;
                f.u[0] = pk_bf(a0.x, a0.y); f.u[1] = pk_bf(a0.z, a0.w);
                f.u[2] = pk_bf(a1.x, a1.y); f.u[3] = pk_bf(a1.z, a1.w);
                S1 = __builtin_amdgcn_mfma_f32_16x16x32_bf16(f.s, Qf[ds], S1, 0, 0, 0);
            }
            int kl0 = kb + quad * 4;
            int kl1 = kb + 16 + quad * 4;
            float s0v[4], s1v[4];
            float mt = m;
            #pragma unroll
            for (int r = 0; r < 4; ++r) {
                s0v[r] = (kl0 + r < kend) ? S0[r] * SCALE : NEGINF;
                s1v[r] = (kl1 + r < kend) ? S1[r] * SCALE : NEGINF;
                mt = fmaxf(mt, fmaxf(s0v[r], s1v[r]));
            }
            mt = fmaxf(mt, __shfl_xor(mt, 16));
            mt = fmaxf(mt, __shfl_xor(mt, 32));
            float alpha = __expf(m - mt);
            m = mt;
            float p0[4], p1[4], ps = 0.f;
            #pragma unroll
            for (int r = 0; r < 4; ++r) {
                p0[r] = __expf(s0v[r] - mt);
                p1[r] = __expf(s1v[r] - mt);
                ps += p0[r] + p1[r];
            }
            ps += __shfl_xor(ps, 16);
            ps += __shfl_xor(ps, 32);
            l = l * alpha + ps;
            #pragma unroll
            for (int dt = 0; dt < 8; ++dt) {
                #pragma unroll
                for (int r = 0; r < 4; ++r) O[dt][r] *= alpha;
            }
            {
                uint2 w0, w1;
                w0.x = pk_bf(p0[0], p0[1]); w0.y = pk_bf(p0[2], p0[3]);
                w1.x = pk_bf(p1[0], p1[1]); w1.y = pk_bf(p1[2], p1[3]);
                *(uint2*)&sPw[l16 * PSTR + quad * 4]      = w0;
                *(uint2*)&sPw[l16 * PSTR + 16 + quad * 4] = w1;
            }
            short8 Pf = *(const short8*)&sPw[l16 * PSTR + quad * 8];
            int vro[8];
            #pragma unroll
            for (int jj = 0; jj < 8; ++jj) {
                int kk = kb + quad * 8 + jj;
                kk = kk < SEQ ? kk : SEQ - 1;
                vro[jj] = kk * DIM;
            }
            const float* vb = v + bo + l16;
            #pragma unroll
            for (int dt = 0; dt < 8; ++dt) {
                int c = dt * 16;
                float x0 = vb[vro[0] + c], x1 = vb[vro[1] + c];
                float x2 = vb[vro[2] + c], x3 = vb[vro[3] + c];
                float x4 = vb[vro[4] + c], x5 = vb[vro[5] + c];
                float x6 = vb[vro[6] + c], x7 = vb[vro[7] + c];
                U8 f;
                f.u[0] = pk_bf(x0, x1); f.u[1] = pk_bf(x2, x3);
                f.u[2] = pk_bf(x4, x5); f.u[3] = pk_bf(x6, x7);
                O[dt] = __builtin_amdgcn_mfma_f32_16x16x32_bf16(f.s, Pf, O[dt], 0, 0, 0);
            }
        }
    }

    if (active && ks > 0) {
        if (quad == 0) { sS[qt][ks][l16][0] = m; sS[qt][ks][l16][1] = l; }
        #pragma unroll
        for (int dt = 0; dt < 8; ++dt)
            *(floatx4*)&sC[qt][ks - 1][l16][dt * 16 + quad * 4] = O[dt];
    }
    __syncthreads();

    if (ks == 0) {
        const float* vm = vmean + b * DIM;
        float* ob = out + bo + (rowbase + l16) * DIM;
        if (active) {
            float mw[3], lw[3];
            float mstar = m;
            #pragma unroll
            for (int w = 0; w < 3; ++w) {
                mw[w] = sS[qt][w + 1][l16][0];
                lw[w] = sS[qt][w + 1][l16][1];
                mstar = fmaxf(mstar, mw[w]);
            }
            float s0 = __expf(m - mstar);
            float sw[3];
            float lstar = s0 * l;
            #pragma unroll
            for (int w = 0; w < 3; ++w) {
                sw[w] = __expf(mw[w] - mstar);
                lstar += sw[w] * lw[w];
            }
            float inv = 1.f / lstar;
            bool rowvalid = (rowbase + l16) < len;
            #pragma unroll
            for (int dt = 0; dt < 8; ++dt) {
                floatx4 acc = O[dt];
                #pragma unroll
                for (int r = 0; r < 4; ++r) acc[r] *= s0;
                #pragma unroll
                for (int w = 0; w < 3; ++w) {
                    floatx4 ow = *(const floatx4*)&sC[qt][w][l16][dt * 16 + quad * 4];
                    #pragma unroll
                    for (int r = 0; r < 4; ++r) acc[r] += sw[w] * ow[r];
                }
                float4 res;
                if (rowvalid) {
                    res = make_float4(acc[0] * inv, acc[1] * inv, acc[2] * inv, acc[3] * inv);
                } else {
                    res = *(const float4*)(vm + dt * 16 + quad * 4);
                }
                *(float4*)(ob + dt * 16 + quad * 4) = res;
            }
        } else {
            #pragma unroll
            for (int dt = 0; dt < 8; ++dt)
                *(float4*)(ob + dt * 16 + quad * 4) =
                    *(const float4*)(vm + dt * 16 + quad * 4);
        }
    }
}

extern "C" void kernel_launch(void* const* d_in, const int* in_sizes, int n_in,
                              void* d_out, int out_size, void* d_ws, size_t ws_size,
                              hipStream_t stream) {
    const float* q = (const float*)d_in[0];
    const float* k = (const float*)d_in[1];
    const float* v = (const float*)d_in[2];
    const int* lens = (const int*)d_in[3];
    float* out = (float*)d_out;

    const size_t kv_elems = (size_t)BATCH * SEQ * DIM;
    const size_t needed = 4096 + 2 * kv_elems * sizeof(unsigned short);

    if (ws_size >= needed) {
        float* vsum = (float*)d_ws;                                   // 4 KB
        unsigned short* kbf = (unsigned short*)((char*)d_ws + 4096);  // 4 MB
        unsigned short* vt = kbf + kv_elems;                          // 4 MB
        hipMemsetAsync(d_ws, 0, 4096, stream);
        conv_kernel<<<dim3(256), dim3(256), 0, stream>>>(k, v, kbf, vt, vsum);
        attn_mx<<<dim3(1024), dim3(256), 0, stream>>>(q, kbf, vt, lens, vsum, out);
    } else {
        float* part = (float*)d_ws;
        float* vmean = part + 64 * DIM;
        vmean_partial<<<dim3(64), dim3(256), 0, stream>>>(v, part);
        vmean_combine<<<dim3(8), dim3(128), 0, stream>>>(part, vmean);
        attn_flash<<<dim3(512), dim3(512), 0, stream>>>(q, k, v, lens, vmean, out);
    }
}

// Round 5
// 136.458 us; speedup vs baseline: 1.5858x; 1.4460x over previous
//
#include <hip/hip_runtime.h>
#include <math.h>

#define BATCH 8
#define SEQ 2048
#define DIM 128
#define SCALE 0.08838834764831845f  // 1/sqrt(128)
#define NEGINF (-1e30f)
#define PSTR 40

typedef __attribute__((ext_vector_type(8))) short short8;
typedef __attribute__((ext_vector_type(4))) float floatx4;

union U8 { unsigned u[4]; short8 s; };

// pack two f32 -> bf16 pair (round-half-up)
__device__ __forceinline__ unsigned pk_bf(float f0, float f1) {
    unsigned a = __float_as_uint(f0) + 0x8000u;
    unsigned b = __float_as_uint(f1) + 0x8000u;
    return __builtin_amdgcn_perm(a, b, 0x03020706u);
}

// async global->LDS DMA, 16 B/lane; lds dest = wave-uniform base + lane*16
__device__ __forceinline__ void gld16(const unsigned short* g, unsigned short* l) {
    __builtin_amdgcn_global_load_lds(
        (const __attribute__((address_space(1))) unsigned*)g,
        (__attribute__((address_space(3))) unsigned*)l, 16, 0, 0);
}
__device__ __forceinline__ void wait_vm0()  { asm volatile("s_waitcnt vmcnt(0)" ::: "memory"); }
__device__ __forceinline__ void wait_lgk0() { asm volatile("s_waitcnt lgkmcnt(0)" ::: "memory"); }

// =================== pre-pass: K*SCALE -> bf16 swizzled rows; V -> bf16 [b][d][s] ===================
// blocks 0..1023: K convert (16 rows each). blocks 1024..1279: V transpose (64-key tile).
__global__ __launch_bounds__(256) void conv_kernel(const float* __restrict__ k,
                                                   const float* __restrict__ v,
                                                   unsigned short* __restrict__ kbf,
                                                   unsigned short* __restrict__ vt) {
    __shared__ unsigned short sT[64 * 136];
    int blk = blockIdx.x, t = threadIdx.x;
    if (blk < 1024) {
        int R = blk * 16 + (t >> 4);      // global K row (b*2048+key)
        int c = t & 15;                   // 16B slot within row
        const float4* k4 = (const float4*)k;
        float4 x0 = k4[R * 32 + c * 2];
        float4 x1 = k4[R * 32 + c * 2 + 1];
        int p = c ^ (R & 7);              // XOR-slot swizzle (bank-balance LDS frag reads)
        uint4 o;
        o.x = pk_bf(x0.x * SCALE, x0.y * SCALE);
        o.y = pk_bf(x0.z * SCALE, x0.w * SCALE);
        o.z = pk_bf(x1.x * SCALE, x1.y * SCALE);
        o.w = pk_bf(x1.z * SCALE, x1.w * SCALE);
        *(uint4*)(kbf + (size_t)R * DIM + p * 8) = o;
    } else {
        int blk2 = blk - 1024;
        int b = blk2 >> 5, k0 = (blk2 & 31) * 64;
        int c = t & 15;
        const float4* v4 = (const float4*)v;
        #pragma unroll
        for (int it = 0; it < 4; ++it) {
            int key = it * 16 + (t >> 4);
            size_t gi = ((size_t)(b * SEQ + k0 + key)) * 32 + c * 2;
            float4 x0 = v4[gi], x1 = v4[gi + 1];
            uint4 o;
            o.x = pk_bf(x0.x, x0.y); o.y = pk_bf(x0.z, x0.w);
            o.z = pk_bf(x1.x, x1.y); o.w = pk_bf(x1.z, x1.w);
            *(uint4*)(sT + key * 136 + c * 8) = o;
        }
        __syncthreads();
        int d = t >> 1, half = t & 1;
        unsigned dw[16];
        #pragma unroll
        for (int i = 0; i < 16; ++i) {
            int key = half * 32 + i * 2;
            unsigned u0 = sT[key * 136 + d];
            unsigned u1 = sT[(key + 1) * 136 + d];
            dw[i] = u0 | (u1 << 16);
        }
        unsigned short* dst = vt + ((size_t)b * DIM + d) * SEQ + k0 + half * 32;
        #pragma unroll
        for (int i = 0; i < 4; ++i)
            *(uint4*)(dst + i * 8) = make_uint4(dw[i*4], dw[i*4+1], dw[i*4+2], dw[i*4+3]);
    }
}

// =================== vmean (averaged) ===================
__global__ __launch_bounds__(256) void vmean_partial(const float* __restrict__ v,
                                                     float* __restrict__ part) {
    int blk = blockIdx.x;
    int b = blk >> 3, oct = blk & 7;
    int t = threadIdx.x;
    int d4 = t & 31, rg = t >> 5;
    const float4* vb = (const float4*)(v + (size_t)b * SEQ * DIM);
    float4 acc = make_float4(0.f, 0.f, 0.f, 0.f);
    int base = oct * 256 + rg * 32;
    #pragma unroll 8
    for (int i = 0; i < 32; ++i) {
        float4 x = vb[(size_t)(base + i) * 32 + d4];
        acc.x += x.x; acc.y += x.y; acc.z += x.z; acc.w += x.w;
    }
    __shared__ float4 red[8][32];
    red[rg][d4] = acc;
    __syncthreads();
    if (t < 32) {
        float4 s = red[0][t];
        #pragma unroll
        for (int r = 1; r < 8; ++r) {
            float4 x = red[r][t];
            s.x += x.x; s.y += x.y; s.z += x.z; s.w += x.w;
        }
        ((float4*)part)[(size_t)blk * 32 + t] = s;
    }
}

__global__ __launch_bounds__(128) void vmean_combine(const float* __restrict__ part,
                                                     float* __restrict__ vmean) {
    int b = blockIdx.x, t = threadIdx.x;
    float s = 0.f;
    #pragma unroll
    for (int o = 0; o < 8; ++o) s += part[((size_t)b * 8 + o) * DIM + t];
    vmean[b * DIM + t] = s * (1.0f / SEQ);
}

// =================== MFMA flash attention, DMA-staged LDS ===================
// Block = 256 thr = 4 waves = 1 q-tile (16 rows) x 4 key-slices. Grid = 8*128.
// Per wave: 32-key chunks; K tile (8KB) + V^T tile (8KB) DMA'd into wave-local LDS.
// S^T = Kbf.Q^T (scale in K); O^T = V^T.P^T; stats per-lane. No barriers in K-loop.
__global__ __launch_bounds__(256, 2) void attn_dma(const float* __restrict__ q,
                                                   const unsigned short* __restrict__ kbf,
                                                   const unsigned short* __restrict__ vt,
                                                   const int* __restrict__ lens,
                                                   const float* __restrict__ vmean,
                                                   float* __restrict__ out) {
    // 4 x (8KB sK + 8KB sVt) staging + 4 x 1280B sP = 70656 B
    __shared__ __align__(16) unsigned char smem[4 * 16384 + 4 * 16 * PSTR * 2];

    int blk = blockIdx.x;
    int b = blk & 7;
    int q0 = (blk >> 3) * 16;
    int len = lens[b];
    int t = threadIdx.x;
    int lane = t & 63;
    int ks = t >> 6;
    int l16 = lane & 15;
    int quad = lane >> 4;
    const int bo = b * SEQ * DIM;

    if (q0 >= len) {                 // block-uniform early exit: vmean rows
        int row = t >> 4;
        int c0 = (t & 15) * 8;
        float4 a = *(const float4*)&vmean[b * DIM + c0];
        float4 c = *(const float4*)&vmean[b * DIM + c0 + 4];
        float* op = out + bo + (q0 + row) * DIM + c0;
        *(float4*)op = a;
        *(float4*)(op + 4) = c;
        return;
    }

    unsigned short* sKw = (unsigned short*)(smem + ks * 16384);
    unsigned short* sVw = sKw + 8192 / 2;
    unsigned short* sPw = (unsigned short*)(smem + 65536) + ks * 16 * PSTR;

    int slice = ((len + 127) >> 7) << 5;   // 32-aligned key slice
    int kbeg = ks * slice;
    int kend = min(kbeg + slice, len);

    floatx4 O[8];
    #pragma unroll
    for (int dt = 0; dt < 8; ++dt) O[dt] = (floatx4){0.f, 0.f, 0.f, 0.f};
    float m = NEGINF, l = 0.f;

    const unsigned short* kB = kbf + (size_t)bo;
    const unsigned short* vB = vt + (size_t)b * DIM * SEQ;

    if (kbeg < kend) {
        // Q B-frags: B[k=d][n=qrow=l16], d = ds*32 + quad*8 + jj
        short8 Qf[4];
        {
            const float* qp = q + bo + (q0 + l16) * DIM + quad * 8;
            #pragma unroll
            for (int ds = 0; ds < 4; ++ds) {
                float4 x0 = *(const float4*)(qp + ds * 32);
                float4 x1 = *(const float4*)(qp + ds * 32 + 4);
                U8 f;
                f.u[0] = pk_bf(x0.x, x0.y); f.u[1] = pk_bf(x0.z, x0.w);
                f.u[2] = pk_bf(x1.x, x1.y); f.u[3] = pk_bf(x1.z, x1.w);
                Qf[ds] = f.s;
            }
        }

        // prologue DMA for first chunk
        {
            int kb = kbeg;
            #pragma unroll
            for (int j = 0; j < 8; ++j)
                gld16(kB + kb * DIM + j * 512 + lane * 8, sKw + j * 512);
            #pragma unroll
            for (int j = 0; j < 8; ++j)
                gld16(vB + (size_t)(j * 16 + (lane >> 2)) * SEQ + kb + (lane & 3) * 8,
                      sVw + j * 512);
        }

        for (int kb = kbeg; kb < kend; kb += 32) {
            wait_vm0();   // staging complete

            // ---- QK^T: 2 ntiles x 4 ds; K frags from swizzled LDS rows ----
            floatx4 S0 = (floatx4){0.f, 0.f, 0.f, 0.f};
            floatx4 S1 = (floatx4){0.f, 0.f, 0.f, 0.f};
            #pragma unroll
            for (int ds = 0; ds < 4; ++ds) {
                int p = ((ds * 4 + quad) ^ (l16 & 7)) * 8;
                short8 K0 = *(const short8*)(sKw + l16 * DIM + p);
                short8 K1 = *(const short8*)(sKw + (16 + l16) * DIM + p);
                S0 = __builtin_amdgcn_mfma_f32_16x16x32_bf16(K0, Qf[ds], S0, 0, 0, 0);
                S1 = __builtin_amdgcn_mfma_f32_16x16x32_bf16(K1, Qf[ds], S1, 0, 0, 0);
            }

            // ---- V^T A-frags to regs (contiguous b128, bank-balanced) ----
            short8 Vf[8];
            #pragma unroll
            for (int dt = 0; dt < 8; ++dt)
                Vf[dt] = *(const short8*)(sVw + (dt * 16 + l16) * 32 + quad * 8);

            // ---- prefetch next chunk (overlaps softmax + PV) ----
            if (kb + 32 < kend) {
                wait_lgk0();   // all staging ds_reads retired before overwrite
                int kn = kb + 32;
                #pragma unroll
                for (int j = 0; j < 8; ++j)
                    gld16(kB + kn * DIM + j * 512 + lane * 8, sKw + j * 512);
                #pragma unroll
                for (int j = 0; j < 8; ++j)
                    gld16(vB + (size_t)(j * 16 + (lane >> 2)) * SEQ + kn + (lane & 3) * 8,
                          sVw + j * 512);
            }

            // ---- online softmax (per-lane stats, reduce across quads) ----
            int kl0 = kb + quad * 4;
            int kl1 = kl0 + 16;
            float s0v[4], s1v[4];
            float mt = m;
            #pragma unroll
            for (int r = 0; r < 4; ++r) {
                s0v[r] = (kl0 + r < kend) ? S0[r] : NEGINF;
                s1v[r] = (kl1 + r < kend) ? S1[r] : NEGINF;
                mt = fmaxf(mt, fmaxf(s0v[r], s1v[r]));
            }
            mt = fmaxf(mt, __shfl_xor(mt, 16));
            mt = fmaxf(mt, __shfl_xor(mt, 32));
            float alpha = __expf(m - mt);
            m = mt;
            float p0[4], p1[4], ps = 0.f;
            #pragma unroll
            for (int r = 0; r < 4; ++r) {
                p0[r] = __expf(s0v[r] - mt);
                p1[r] = __expf(s1v[r] - mt);
                ps += p0[r] + p1[r];
            }
            ps += __shfl_xor(ps, 16);
            ps += __shfl_xor(ps, 32);
            l = l * alpha + ps;
            #pragma unroll
            for (int dt = 0; dt < 8; ++dt) {
                #pragma unroll
                for (int r = 0; r < 4; ++r) O[dt][r] *= alpha;
            }

            // ---- P^T C->B layout via wave-local LDS round trip ----
            {
                uint2 w0, w1;
                w0.x = pk_bf(p0[0], p0[1]); w0.y = pk_bf(p0[2], p0[3]);
                w1.x = pk_bf(p1[0], p1[1]); w1.y = pk_bf(p1[2], p1[3]);
                *(uint2*)&sPw[l16 * PSTR + quad * 4]      = w0;
                *(uint2*)&sPw[l16 * PSTR + 16 + quad * 4] = w1;
            }
            short8 Pf = *(const short8*)&sPw[l16 * PSTR + quad * 8];

            // ---- PV ----
            #pragma unroll
            for (int dt = 0; dt < 8; ++dt)
                O[dt] = __builtin_amdgcn_mfma_f32_16x16x32_bf16(Vf[dt], Pf, O[dt], 0, 0, 0);
        }
    }

    // ---- cross-slice combine (sC aliases staging LDS; barrier-protected) ----
    float (*sC)[16][132] = (float(*)[16][132])smem;             // 3*16*132*4 = 25344 B
    float (*sS)[2] = (float(*)[2])(smem + 25344);               // [4*16][2]

    __syncthreads();   // everyone done with staging LDS
    if (ks > 0) {
        if (quad == 0) { sS[ks * 16 + l16][0] = m; sS[ks * 16 + l16][1] = l; }
        #pragma unroll
        for (int dt = 0; dt < 8; ++dt)
            *(floatx4*)&sC[ks - 1][l16][dt * 16 + quad * 4] = O[dt];
    }
    __syncthreads();

    if (ks == 0) {
        float mw[3], lw[3];
        float mstar = m;
        #pragma unroll
        for (int w = 0; w < 3; ++w) {
            mw[w] = sS[(w + 1) * 16 + l16][0];
            lw[w] = sS[(w + 1) * 16 + l16][1];
            mstar = fmaxf(mstar, mw[w]);
        }
        float s0 = __expf(m - mstar);
        float sw[3];
        float lstar = s0 * l;
        #pragma unroll
        for (int w = 0; w < 3; ++w) {
            sw[w] = __expf(mw[w] - mstar);
            lstar += sw[w] * lw[w];
        }
        float inv = 1.f / lstar;
        bool rowvalid = (q0 + l16) < len;
        float* ob = out + bo + (q0 + l16) * DIM;
        const float* vm = vmean + b * DIM;
        #pragma unroll
        for (int dt = 0; dt < 8; ++dt) {
            floatx4 acc = O[dt];
            #pragma unroll
            for (int r = 0; r < 4; ++r) acc[r] *= s0;
            #pragma unroll
            for (int w = 0; w < 3; ++w) {
                floatx4 ow = *(const floatx4*)&sC[w][l16][dt * 16 + quad * 4];
                #pragma unroll
                for (int r = 0; r < 4; ++r) acc[r] += sw[w] * ow[r];
            }
            float4 res;
            if (rowvalid) {
                res = make_float4(acc[0] * inv, acc[1] * inv, acc[2] * inv, acc[3] * inv);
            } else {
                res = *(const float4*)(vm + dt * 16 + quad * 4);
            }
            *(float4*)(ob + dt * 16 + quad * 4) = res;
        }
    }
}

// =================== fallback path (ws too small): R3 kernel ===================
__global__ __launch_bounds__(512, 4) void attn_flash(const float* __restrict__ q,
                                                     const float* __restrict__ k,
                                                     const float* __restrict__ v,
                                                     const int* __restrict__ lens,
                                                     const float* __restrict__ vmean,
                                                     float* __restrict__ out) {
    __shared__ unsigned short sPf[8 * 16 * PSTR];
    __shared__ float sC[2][3][16][132];
    __shared__ float sS[2][4][16][2];

    int blk = blockIdx.x;
    int b = blk & 7;
    int g = blk >> 3;
    int q0 = g * 32;
    int len = lens[b];
    int t = threadIdx.x;
    int lane = t & 63;
    int wave = t >> 6;
    int qt = wave & 1;
    int ks = wave >> 1;
    int l16 = lane & 15;
    int quad = lane >> 4;
    const int bo = b * SEQ * DIM;

    int rowbase = q0 + qt * 16;
    bool active = q0 < len;

    int slice = (len + 3) >> 2;
    int kbeg = ks * slice;
    int kend = min(kbeg + slice, len);

    floatx4 O[8];
    #pragma unroll
    for (int dt = 0; dt < 8; ++dt) O[dt] = (floatx4){0.f, 0.f, 0.f, 0.f};
    float m = NEGINF, l = 0.f;
    unsigned short* sPw = &sPf[wave * 16 * PSTR];

    if (active && kbeg < kend) {
        short8 Qf[4];
        {
            const float* qp = q + bo + (rowbase + l16) * DIM + quad * 8;
            #pragma unroll
            for (int ds = 0; ds < 4; ++ds) {
                float4 x0 = *(const float4*)(qp + ds * 32);
                float4 x1 = *(const float4*)(qp + ds * 32 + 4);
                U8 f;
                f.u[0] = pk_bf(x0.x, x0.y); f.u[1] = pk_bf(x0.z, x0.w);
                f.u[2] = pk_bf(x1.x, x1.y); f.u[3] = pk_bf(x1.z, x1.w);
                Qf[ds] = f.s;
            }
        }
        for (int kb = kbeg; kb < kend; kb += 32) {
            int kr0 = kb + l16;      kr0 = kr0 < SEQ ? kr0 : SEQ - 1;
            int kr1 = kb + 16 + l16; kr1 = kr1 < SEQ ? kr1 : SEQ - 1;
            const float* kp0 = k + bo + kr0 * DIM + quad * 8;
            const float* kp1 = k + bo + kr1 * DIM + quad * 8;
            floatx4 S0 = (floatx4){0.f, 0.f, 0.f, 0.f};
            floatx4 S1 = (floatx4){0.f, 0.f, 0.f, 0.f};
            #pragma unroll
            for (int ds = 0; ds < 4; ++ds) {
                float4 a0 = *(const float4*)(kp0 + ds * 32);
                float4 a1 = *(const float4*)(kp0 + ds * 32 + 4);
                U8 f;
                f.u[0] = pk_bf(a0.x, a0.y); f.u[1] = pk_bf(a0.z, a0.w);
                f.u[2] = pk_bf(a1.x, a1.y); f.u[3] = pk_bf(a1.z, a1.w);
                S0 = __builtin_amdgcn_mfma_f32_16x16x32_bf16(f.s, Qf[ds], S0, 0, 0, 0);
            }
            #pragma unroll
            for (int ds = 0; ds < 4; ++ds) {
                float4 a0 = *(const float4*)(kp1 + ds * 32);
                float4 a1 = *(const float4*)(kp1 + ds * 32 + 4);
                U8 f;
                f.u[0] = pk_bf(a0.x, a0.y); f.u[1] = pk_bf(a0.z, a0.w);
                f.u[2] = pk_bf(a1.x, a1.y); f.u[3] = pk_bf(a1.z, a1.w);
                S1 = __builtin_amdgcn_mfma_f32_16x16x32_bf16(f.s, Qf[ds], S1, 0, 0, 0);
            }
            int kl0 = kb + quad * 4;
            int kl1 = kb + 16 + quad * 4;
            float s0v[4], s1v[4];
            float mt = m;
            #pragma unroll
            for (int r = 0; r < 4; ++r) {
                s0v[r] = (kl0 + r < kend) ? S0[r] * SCALE : NEGINF;
                s1v[r] = (kl1 + r < kend) ? S1[r] * SCALE : NEGINF;
                mt = fmaxf(mt, fmaxf(s0v[r], s1v[r]));
            }
            mt = fmaxf(mt, __shfl_xor(mt, 16));
            mt = fmaxf(mt, __shfl_xor(mt, 32));
            float alpha = __expf(m - mt);
            m = mt;
            float p0[4], p1[4], ps = 0.f;
            #pragma unroll
            for (int r = 0; r < 4; ++r) {
                p0[r] = __expf(s0v[r] - mt);
                p1[r] = __expf(s1v[r] - mt);
                ps += p0[r] + p1[r];
            }
            ps += __shfl_xor(ps, 16);
            ps += __shfl_xor(ps, 32);
            l = l * alpha + ps;
            #pragma unroll
            for (int dt = 0; dt < 8; ++dt) {
                #pragma unroll
                for (int r = 0; r < 4; ++r) O[dt][r] *= alpha;
            }
            {
                uint2 w0, w1;
                w0.x = pk_bf(p0[0], p0[1]); w0.y = pk_bf(p0[2], p0[3]);
                w1.x = pk_bf(p1[0], p1[1]); w1.y = pk_bf(p1[2], p1[3]);
                *(uint2*)&sPw[l16 * PSTR + quad * 4]      = w0;
                *(uint2*)&sPw[l16 * PSTR + 16 + quad * 4] = w1;
            }
            short8 Pf = *(const short8*)&sPw[l16 * PSTR + quad * 8];
            int vro[8];
            #pragma unroll
            for (int jj = 0; jj < 8; ++jj) {
                int kk = kb + quad * 8 + jj;
                kk = kk < SEQ ? kk : SEQ - 1;
                vro[jj] = kk * DIM;
            }
            const float* vb = v + bo + l16;
            #pragma unroll
            for (int dt = 0; dt < 8; ++dt) {
                int c = dt * 16;
                float x0 = vb[vro[0] + c], x1 = vb[vro[1] + c];
                float x2 = vb[vro[2] + c], x3 = vb[vro[3] + c];
                float x4 = vb[vro[4] + c], x5 = vb[vro[5] + c];
                float x6 = vb[vro[6] + c], x7 = vb[vro[7] + c];
                U8 f;
                f.u[0] = pk_bf(x0, x1); f.u[1] = pk_bf(x2, x3);
                f.u[2] = pk_bf(x4, x5); f.u[3] = pk_bf(x6, x7);
                O[dt] = __builtin_amdgcn_mfma_f32_16x16x32_bf16(f.s, Pf, O[dt], 0, 0, 0);
            }
        }
    }

    if (active && ks > 0) {
        if (quad == 0) { sS[qt][ks][l16][0] = m; sS[qt][ks][l16][1] = l; }
        #pragma unroll
        for (int dt = 0; dt < 8; ++dt)
            *(floatx4*)&sC[qt][ks - 1][l16][dt * 16 + quad * 4] = O[dt];
    }
    __syncthreads();

    if (ks == 0) {
        const float* vm = vmean + b * DIM;
        float* ob = out + bo + (rowbase + l16) * DIM;
        if (active) {
            float mw[3], lw[3];
            float mstar = m;
            #pragma unroll
            for (int w = 0; w < 3; ++w) {
                mw[w] = sS[qt][w + 1][l16][0];
                lw[w] = sS[qt][w + 1][l16][1];
                mstar = fmaxf(mstar, mw[w]);
            }
            float s0 = __expf(m - mstar);
            float sw[3];
            float lstar = s0 * l;
            #pragma unroll
            for (int w = 0; w < 3; ++w) {
                sw[w] = __expf(mw[w] - mstar);
                lstar += sw[w] * lw[w];
            }
            float inv = 1.f / lstar;
            bool rowvalid = (rowbase + l16) < len;
            #pragma unroll
            for (int dt = 0; dt < 8; ++dt) {
                floatx4 acc = O[dt];
                #pragma unroll
                for (int r = 0; r < 4; ++r) acc[r] *= s0;
                #pragma unroll
                for (int w = 0; w < 3; ++w) {
                    floatx4 ow = *(const floatx4*)&sC[qt][w][l16][dt * 16 + quad * 4];
                    #pragma unroll
                    for (int r = 0; r < 4; ++r) acc[r] += sw[w] * ow[r];
                }
                float4 res;
                if (rowvalid) {
                    res = make_float4(acc[0] * inv, acc[1] * inv, acc[2] * inv, acc[3] * inv);
                } else {
                    res = *(const float4*)(vm + dt * 16 + quad * 4);
                }
                *(float4*)(ob + dt * 16 + quad * 4) = res;
            }
        } else {
            #pragma unroll
            for (int dt = 0; dt < 8; ++dt)
                *(float4*)(ob + dt * 16 + quad * 4) =
                    *(const float4*)(vm + dt * 16 + quad * 4);
        }
    }
}

extern "C" void kernel_launch(void* const* d_in, const int* in_sizes, int n_in,
                              void* d_out, int out_size, void* d_ws, size_t ws_size,
                              hipStream_t stream) {
    const float* q = (const float*)d_in[0];
    const float* k = (const float*)d_in[1];
    const float* v = (const float*)d_in[2];
    const int* lens = (const int*)d_in[3];
    float* out = (float*)d_out;

    const size_t kv_elems = (size_t)BATCH * SEQ * DIM;
    const size_t head = 64 * DIM * 4 + BATCH * DIM * 4;   // part + vmean
    const size_t needed = head + 2 * kv_elems * sizeof(unsigned short);

    float* part = (float*)d_ws;
    float* vmean = part + 64 * DIM;

    if (ws_size >= needed) {
        unsigned short* kbf = (unsigned short*)((char*)d_ws + head);
        unsigned short* vt = kbf + kv_elems;
        conv_kernel<<<dim3(1280), dim3(256), 0, stream>>>(k, v, kbf, vt);
        vmean_partial<<<dim3(64), dim3(256), 0, stream>>>(v, part);
        vmean_combine<<<dim3(8), dim3(128), 0, stream>>>(part, vmean);
        attn_dma<<<dim3(1024), dim3(256), 0, stream>>>(q, kbf, vt, lens, vmean, out);
    } else {
        vmean_partial<<<dim3(64), dim3(256), 0, stream>>>(v, part);
        vmean_combine<<<dim3(8), dim3(128), 0, stream>>>(part, vmean);
        attn_flash<<<dim3(512), dim3(512), 0, stream>>>(q, k, v, lens, vmean, out);
    }
}

// Round 6
// 128.656 us; speedup vs baseline: 1.6820x; 1.0606x over previous
//
#include <hip/hip_runtime.h>
#include <math.h>

#define BATCH 8
#define SEQ 2048
#define DIM 128
#define SCALE 0.08838834764831845f  // 1/sqrt(128)
#define NEGINF (-1e30f)
#define PSTR 40
#define INVSEQ (1.0f / 2048.0f)

// workspace byte offsets
#define OFF_VPART 0            // 8*64*128 floats = 256 KB
#define OFF_VMEAN 262144       // 8*128 floats = 4 KB
#define OFF_KW    266240       // 8*64*8KB = 4 MB  (frag-major bf16, *SCALE)
#define OFF_VW    4460544      // 4 MB              (frag-major bf16 V^T)
#define WS_NEEDED 8654848

typedef __attribute__((ext_vector_type(8))) short short8;
typedef __attribute__((ext_vector_type(4))) float floatx4;

union U8 { unsigned u[4]; short8 s; uint4 q; };

__device__ __forceinline__ unsigned pk_bf(float f0, float f1) {
    unsigned a = __float_as_uint(f0) + 0x8000u;
    unsigned b = __float_as_uint(f1) + 0x8000u;
    return __builtin_amdgcn_perm(a, b, 0x03020706u);
}
__device__ __forceinline__ unsigned short bf1(float f) {
    return (unsigned short)((__float_as_uint(f) + 0x8000u) >> 16);
}

// =================== pre-pass: frag-major K and V^T tiles ===================
// blocks 0..511: K tiles.  blocks 512..1023: V tiles (+ per-tile vmean partials).
// Tile = 32 keys. kw record (f,lane): K[t32+nt*16+l16][ds*32+quad*8+jj]*SCALE,
// f=nt*4+ds, lane=quad*16+l16.  vw record (dt,lane): V[t32+quad*8+jj][dt*16+l16].
__global__ __launch_bounds__(256) void conv2(const float* __restrict__ k,
                                             const float* __restrict__ v,
                                             unsigned short* __restrict__ kw,
                                             unsigned short* __restrict__ vw,
                                             float* __restrict__ vpart) {
    __shared__ __align__(16) unsigned short sB[128 * 40];  // V: transpose tile (10 KB); K: frag buffer (8 KB)
    int blk = blockIdx.x, tt = threadIdx.x;
    if (blk < 512) {
        int b = blk >> 6, tile = blk & 63;
        int r = tt >> 3, cb = tt & 7;       // row 0..31, 16-col block
        const float* kp = k + ((size_t)(b * SEQ + tile * 32 + r)) * DIM + cb * 16;
        float4 x0 = *(const float4*)(kp + 0);
        float4 x1 = *(const float4*)(kp + 4);
        float4 x2 = *(const float4*)(kp + 8);
        float4 x3 = *(const float4*)(kp + 12);
        uint4* sF = (uint4*)sB;
        int nt = r >> 4, l16 = r & 15, ds = cb >> 1, qb = (cb & 1) * 2;
        int pos = (nt * 4 + ds) * 64 + qb * 16 + l16;
        uint4 o0, o1;
        o0.x = pk_bf(x0.x * SCALE, x0.y * SCALE); o0.y = pk_bf(x0.z * SCALE, x0.w * SCALE);
        o0.z = pk_bf(x1.x * SCALE, x1.y * SCALE); o0.w = pk_bf(x1.z * SCALE, x1.w * SCALE);
        o1.x = pk_bf(x2.x * SCALE, x2.y * SCALE); o1.y = pk_bf(x2.z * SCALE, x2.w * SCALE);
        o1.z = pk_bf(x3.x * SCALE, x3.y * SCALE); o1.w = pk_bf(x3.z * SCALE, x3.w * SCALE);
        sF[pos] = o0;
        sF[pos + 16] = o1;
        __syncthreads();
        uint4* dst = (uint4*)(kw + (size_t)(b * 64 + tile) * 4096);
        dst[tt * 2] = sF[tt * 2];
        dst[tt * 2 + 1] = sF[tt * 2 + 1];
    } else {
        int blk2 = blk - 512;
        int b = blk2 >> 6, tile = blk2 & 63;
        int r = tt >> 3, cb = tt & 7;
        const float* vp = v + ((size_t)(b * SEQ + tile * 32 + r)) * DIM + cb * 16;
        float4 x0 = *(const float4*)(vp + 0);
        float4 x1 = *(const float4*)(vp + 4);
        float4 x2 = *(const float4*)(vp + 8);
        float4 x3 = *(const float4*)(vp + 12);
        float xs[16] = {x0.x,x0.y,x0.z,x0.w, x1.x,x1.y,x1.z,x1.w,
                        x2.x,x2.y,x2.z,x2.w, x3.x,x3.y,x3.z,x3.w};
        #pragma unroll
        for (int i = 0; i < 16; ++i)
            sB[(cb * 16 + i) * 40 + r] = bf1(xs[i]);
        __syncthreads();
        // per-tile column sums (from bf16; rounding error negligible after /2048)
        if (tt < 128) {
            float s = 0.f;
            #pragma unroll
            for (int key = 0; key < 32; ++key)
                s += __uint_as_float(((unsigned)sB[tt * 40 + key]) << 16);
            vpart[(size_t)(b * 64 + tile) * 128 + tt] = s;
        }
        // frag-major store: position p = dt*64 + quad*16 + l16
        uint4* dst = (uint4*)(vw + (size_t)(b * 64 + tile) * 4096);
        #pragma unroll
        for (int h = 0; h < 2; ++h) {
            int p = tt * 2 + h;
            int dt = p >> 6, l16 = p & 15, quad = (p >> 4) & 3;
            U8 f;
            f.s = *(const short8*)&sB[(dt * 16 + l16) * 40 + quad * 8];
            dst[p] = f.q;
        }
    }
}

__global__ __launch_bounds__(128) void vmean2(const float* __restrict__ vpart,
                                              float* __restrict__ vmean) {
    int b = blockIdx.x, t = threadIdx.x;
    float s = 0.f;
    for (int tile = 0; tile < 64; ++tile)
        s += vpart[(size_t)(b * 64 + tile) * 128 + t];
    vmean[b * DIM + t] = s * INVSEQ;
}

// =================== MFMA flash attention, frag-major direct loads ===================
// Block = 256 thr = 4 waves = 1 q-tile (16 rows) x 4 key-slices. Grid = 8*128.
// All MFMA operands load as contiguous 1KB global dwordx4 (L2-hot). LDS only for
// the P C->B round trip and the cross-slice combine.
__global__ __launch_bounds__(256, 4) void attn_fm(const float* __restrict__ q,
                                                  const unsigned short* __restrict__ kw,
                                                  const unsigned short* __restrict__ vw,
                                                  const int* __restrict__ lens,
                                                  const float* __restrict__ vmean,
                                                  float* __restrict__ out) {
    __shared__ __align__(16) unsigned short sP[4][16 * PSTR];  // 5120 B
    __shared__ float sC[3][16][132];                           // 25344 B
    __shared__ float sS[4][16][2];                             // 512 B

    int blk = blockIdx.x;
    int b = blk & 7;
    int q0 = (blk >> 3) * 16;
    int len = lens[b];
    int t = threadIdx.x;
    int lane = t & 63;
    int ks = t >> 6;
    int l16 = lane & 15;
    int quad = lane >> 4;
    const int bo = b * SEQ * DIM;

    if (q0 >= len) {                 // block-uniform early exit: vmean rows
        int row = t >> 4;
        int c0 = (t & 15) * 8;
        float4 a = *(const float4*)&vmean[b * DIM + c0];
        float4 c = *(const float4*)&vmean[b * DIM + c0 + 4];
        float* op = out + bo + (q0 + row) * DIM + c0;
        *(float4*)op = a;
        *(float4*)(op + 4) = c;
        return;
    }

    int slice = ((len + 127) >> 7) << 5;   // 32-aligned per-wave key range
    int kbeg = ks * slice;
    int kend = min(kbeg + slice, len);

    floatx4 O[8];
    #pragma unroll
    for (int dt = 0; dt < 8; ++dt) O[dt] = (floatx4){0.f, 0.f, 0.f, 0.f};
    float m = NEGINF, l = 0.f;
    unsigned short* sPw = sP[ks];

    const unsigned short* kwB = kw + (size_t)b * 64 * 4096;
    const unsigned short* vwB = vw + (size_t)b * 64 * 4096;

    if (kbeg < kend) {
        // Q B-frags: B[k=d][n=qrow=l16], d = ds*32 + quad*8 + jj
        short8 Qf[4];
        {
            const float* qp = q + bo + (q0 + l16) * DIM + quad * 8;
            #pragma unroll
            for (int ds = 0; ds < 4; ++ds) {
                float4 x0 = *(const float4*)(qp + ds * 32);
                float4 x1 = *(const float4*)(qp + ds * 32 + 4);
                U8 f;
                f.u[0] = pk_bf(x0.x, x0.y); f.u[1] = pk_bf(x0.z, x0.w);
                f.u[2] = pk_bf(x1.x, x1.y); f.u[3] = pk_bf(x1.z, x1.w);
                Qf[ds] = f.s;
            }
        }

        for (int kb = kbeg; kb < kend; kb += 32) {
            const unsigned short* kT = kwB + (size_t)(kb >> 5) * 4096 + lane * 8;
            const unsigned short* vT = vwB + (size_t)(kb >> 5) * 4096 + lane * 8;

            // ---- K A-frags: 8 contiguous-1KB loads; QK^T ----
            short8 Ka[4], Kb_[4];
            #pragma unroll
            for (int ds = 0; ds < 4; ++ds) Ka[ds] = *(const short8*)(kT + ds * 512);
            floatx4 S0 = (floatx4){0.f, 0.f, 0.f, 0.f};
            floatx4 S1 = (floatx4){0.f, 0.f, 0.f, 0.f};
            #pragma unroll
            for (int ds = 0; ds < 4; ++ds)
                S0 = __builtin_amdgcn_mfma_f32_16x16x32_bf16(Ka[ds], Qf[ds], S0, 0, 0, 0);
            #pragma unroll
            for (int ds = 0; ds < 4; ++ds) Kb_[ds] = *(const short8*)(kT + (4 + ds) * 512);
            #pragma unroll
            for (int ds = 0; ds < 4; ++ds)
                S1 = __builtin_amdgcn_mfma_f32_16x16x32_bf16(Kb_[ds], Qf[ds], S1, 0, 0, 0);

            // ---- V A-frags issue now; latency hides under softmax ----
            short8 Vf[8];
            #pragma unroll
            for (int dt = 0; dt < 8; ++dt) Vf[dt] = *(const short8*)(vT + dt * 512);

            // ---- online softmax (per-lane stats; reduce across quads) ----
            int kl0 = kb + quad * 4;
            int kl1 = kl0 + 16;
            float s0v[4], s1v[4];
            float mt = m;
            #pragma unroll
            for (int r = 0; r < 4; ++r) {
                s0v[r] = (kl0 + r < kend) ? S0[r] : NEGINF;   // scale folded into K
                s1v[r] = (kl1 + r < kend) ? S1[r] : NEGINF;
                mt = fmaxf(mt, fmaxf(s0v[r], s1v[r]));
            }
            mt = fmaxf(mt, __shfl_xor(mt, 16));
            mt = fmaxf(mt, __shfl_xor(mt, 32));
            float alpha = __expf(m - mt);
            m = mt;
            float p0[4], p1[4], ps = 0.f;
            #pragma unroll
            for (int r = 0; r < 4; ++r) {
                p0[r] = __expf(s0v[r] - mt);
                p1[r] = __expf(s1v[r] - mt);
                ps += p0[r] + p1[r];
            }
            ps += __shfl_xor(ps, 16);
            ps += __shfl_xor(ps, 32);
            l = l * alpha + ps;
            #pragma unroll
            for (int dt = 0; dt < 8; ++dt) {
                #pragma unroll
                for (int r = 0; r < 4; ++r) O[dt][r] *= alpha;
            }

            // ---- P^T C->B layout via wave-local LDS round trip ----
            {
                uint2 w0, w1;
                w0.x = pk_bf(p0[0], p0[1]); w0.y = pk_bf(p0[2], p0[3]);
                w1.x = pk_bf(p1[0], p1[1]); w1.y = pk_bf(p1[2], p1[3]);
                *(uint2*)&sPw[l16 * PSTR + quad * 4]      = w0;
                *(uint2*)&sPw[l16 * PSTR + 16 + quad * 4] = w1;
            }
            short8 Pf = *(const short8*)&sPw[l16 * PSTR + quad * 8];

            // ---- PV ----
            #pragma unroll
            for (int dt = 0; dt < 8; ++dt)
                O[dt] = __builtin_amdgcn_mfma_f32_16x16x32_bf16(Vf[dt], Pf, O[dt], 0, 0, 0);
        }
    }

    // ---- cross-slice combine ----
    if (ks > 0) {
        if (quad == 0) { sS[ks][l16][0] = m; sS[ks][l16][1] = l; }
        #pragma unroll
        for (int dt = 0; dt < 8; ++dt)
            *(floatx4*)&sC[ks - 1][l16][dt * 16 + quad * 4] = O[dt];
    }
    __syncthreads();

    if (ks == 0) {
        float mw[3], lw[3];
        float mstar = m;
        #pragma unroll
        for (int w = 0; w < 3; ++w) {
            mw[w] = sS[w + 1][l16][0];
            lw[w] = sS[w + 1][l16][1];
            mstar = fmaxf(mstar, mw[w]);
        }
        float s0 = __expf(m - mstar);
        float sw[3];
        float lstar = s0 * l;
        #pragma unroll
        for (int w = 0; w < 3; ++w) {
            sw[w] = __expf(mw[w] - mstar);
            lstar += sw[w] * lw[w];
        }
        float inv = 1.f / lstar;
        bool rowvalid = (q0 + l16) < len;
        float* ob = out + bo + (q0 + l16) * DIM;
        const float* vm = vmean + b * DIM;
        #pragma unroll
        for (int dt = 0; dt < 8; ++dt) {
            floatx4 acc = O[dt];
            #pragma unroll
            for (int r = 0; r < 4; ++r) acc[r] *= s0;
            #pragma unroll
            for (int w = 0; w < 3; ++w) {
                floatx4 ow = *(const floatx4*)&sC[w][l16][dt * 16 + quad * 4];
                #pragma unroll
                for (int r = 0; r < 4; ++r) acc[r] += sw[w] * ow[r];
            }
            float4 res;
            if (rowvalid) {
                res = make_float4(acc[0] * inv, acc[1] * inv, acc[2] * inv, acc[3] * inv);
            } else {
                res = *(const float4*)(vm + dt * 16 + quad * 4);
            }
            *(float4*)(ob + dt * 16 + quad * 4) = res;
        }
    }
}

// =================== fallback path (ws too small): R3 kernel ===================
__global__ __launch_bounds__(256) void vmean_partial(const float* __restrict__ v,
                                                     float* __restrict__ part) {
    int blk = blockIdx.x;
    int b = blk >> 3, oct = blk & 7;
    int t = threadIdx.x;
    int d4 = t & 31, rg = t >> 5;
    const float4* vb = (const float4*)(v + (size_t)b * SEQ * DIM);
    float4 acc = make_float4(0.f, 0.f, 0.f, 0.f);
    int base = oct * 256 + rg * 32;
    #pragma unroll 8
    for (int i = 0; i < 32; ++i) {
        float4 x = vb[(size_t)(base + i) * 32 + d4];
        acc.x += x.x; acc.y += x.y; acc.z += x.z; acc.w += x.w;
    }
    __shared__ float4 red[8][32];
    red[rg][d4] = acc;
    __syncthreads();
    if (t < 32) {
        float4 s = red[0][t];
        #pragma unroll
        for (int r = 1; r < 8; ++r) {
            float4 x = red[r][t];
            s.x += x.x; s.y += x.y; s.z += x.z; s.w += x.w;
        }
        ((float4*)part)[(size_t)blk * 32 + t] = s;
    }
}

__global__ __launch_bounds__(128) void vmean_combine(const float* __restrict__ part,
                                                     float* __restrict__ vmean) {
    int b = blockIdx.x, t = threadIdx.x;
    float s = 0.f;
    #pragma unroll
    for (int o = 0; o < 8; ++o) s += part[((size_t)b * 8 + o) * DIM + t];
    vmean[b * DIM + t] = s * INVSEQ;
}

__global__ __launch_bounds__(512, 4) void attn_flash(const float* __restrict__ q,
                                                     const float* __restrict__ k,
                                                     const float* __restrict__ v,
                                                     const int* __restrict__ lens,
                                                     const float* __restrict__ vmean,
                                                     float* __restrict__ out) {
    __shared__ unsigned short sPf[8 * 16 * PSTR];
    __shared__ float sC[2][3][16][132];
    __shared__ float sS[2][4][16][2];

    int blk = blockIdx.x;
    int b = blk & 7;
    int g = blk >> 3;
    int q0 = g * 32;
    int len = lens[b];
    int t = threadIdx.x;
    int lane = t & 63;
    int wave = t >> 6;
    int qt = wave & 1;
    int ks = wave >> 1;
    int l16 = lane & 15;
    int quad = lane >> 4;
    const int bo = b * SEQ * DIM;

    int rowbase = q0 + qt * 16;
    bool active = q0 < len;

    int slice = (len + 3) >> 2;
    int kbeg = ks * slice;
    int kend = min(kbeg + slice, len);

    floatx4 O[8];
    #pragma unroll
    for (int dt = 0; dt < 8; ++dt) O[dt] = (floatx4){0.f, 0.f, 0.f, 0.f};
    float m = NEGINF, l = 0.f;
    unsigned short* sPw = &sPf[wave * 16 * PSTR];

    if (active && kbeg < kend) {
        short8 Qf[4];
        {
            const float* qp = q + bo + (rowbase + l16) * DIM + quad * 8;
            #pragma unroll
            for (int ds = 0; ds < 4; ++ds) {
                float4 x0 = *(const float4*)(qp + ds * 32);
                float4 x1 = *(const float4*)(qp + ds * 32 + 4);
                U8 f;
                f.u[0] = pk_bf(x0.x, x0.y); f.u[1] = pk_bf(x0.z, x0.w);
                f.u[2] = pk_bf(x1.x, x1.y); f.u[3] = pk_bf(x1.z, x1.w);
                Qf[ds] = f.s;
            }
        }
        for (int kb = kbeg; kb < kend; kb += 32) {
            int kr0 = kb + l16;      kr0 = kr0 < SEQ ? kr0 : SEQ - 1;
            int kr1 = kb + 16 + l16; kr1 = kr1 < SEQ ? kr1 : SEQ - 1;
            const float* kp0 = k + bo + kr0 * DIM + quad * 8;
            const float* kp1 = k + bo + kr1 * DIM + quad * 8;
            floatx4 S0 = (floatx4){0.f, 0.f, 0.f, 0.f};
            floatx4 S1 = (floatx4){0.f, 0.f, 0.f, 0.f};
            #pragma unroll
            for (int ds = 0; ds < 4; ++ds) {
                float4 a0 = *(const float4*)(kp0 + ds * 32);
                float4 a1 = *(const float4*)(kp0 + ds * 32 + 4);
                U8 f;
                f.u[0] = pk_bf(a0.x, a0.y); f.u[1] = pk_bf(a0.z, a0.w);
                f.u[2] = pk_bf(a1.x, a1.y); f.u[3] = pk_bf(a1.z, a1.w);
                S0 = __builtin_amdgcn_mfma_f32_16x16x32_bf16(f.s, Qf[ds], S0, 0, 0, 0);
            }
            #pragma unroll
            for (int ds = 0; ds < 4; ++ds) {
                float4 a0 = *(const float4*)(kp1 + ds * 32);
                float4 a1 = *(const float4*)(kp1 + ds * 32 + 4);
                U8 f;
                f.u[0] = pk_bf(a0.x, a0.y); f.u[1] = pk_bf(a0.z, a0.w);
                f.u[2] = pk_bf(a1.x, a1.y); f.u[3] = pk_bf(a1.z, a1.w);
                S1 = __builtin_amdgcn_mfma_f32_16x16x32_bf16(f.s, Qf[ds], S1, 0, 0, 0);
            }
            int kl0 = kb + quad * 4;
            int kl1 = kb + 16 + quad * 4;
            float s0v[4], s1v[4];
            float mt = m;
            #pragma unroll
            for (int r = 0; r < 4; ++r) {
                s0v[r] = (kl0 + r < kend) ? S0[r] * SCALE : NEGINF;
                s1v[r] = (kl1 + r < kend) ? S1[r] * SCALE : NEGINF;
                mt = fmaxf(mt, fmaxf(s0v[r], s1v[r]));
            }
            mt = fmaxf(mt, __shfl_xor(mt, 16));
            mt = fmaxf(mt, __shfl_xor(mt, 32));
            float alpha = __expf(m - mt);
            m = mt;
            float p0[4], p1[4], ps = 0.f;
            #pragma unroll
            for (int r = 0; r < 4; ++r) {
                p0[r] = __expf(s0v[r] - mt);
                p1[r] = __expf(s1v[r] - mt);
                ps += p0[r] + p1[r];
            }
            ps += __shfl_xor(ps, 16);
            ps += __shfl_xor(ps, 32);
            l = l * alpha + ps;
            #pragma unroll
            for (int dt = 0; dt < 8; ++dt) {
                #pragma unroll
                for (int r = 0; r < 4; ++r) O[dt][r] *= alpha;
            }
            {
                uint2 w0, w1;
                w0.x = pk_bf(p0[0], p0[1]); w0.y = pk_bf(p0[2], p0[3]);
                w1.x = pk_bf(p1[0], p1[1]); w1.y = pk_bf(p1[2], p1[3]);
                *(uint2*)&sPw[l16 * PSTR + quad * 4]      = w0;
                *(uint2*)&sPw[l16 * PSTR + 16 + quad * 4] = w1;
            }
            short8 Pf = *(const short8*)&sPw[l16 * PSTR + quad * 8];
            int vro[8];
            #pragma unroll
            for (int jj = 0; jj < 8; ++jj) {
                int kk = kb + quad * 8 + jj;
                kk = kk < SEQ ? kk : SEQ - 1;
                vro[jj] = kk * DIM;
            }
            const float* vb = v + bo + l16;
            #pragma unroll
            for (int dt = 0; dt < 8; ++dt) {
                int c = dt * 16;
                float x0 = vb[vro[0] + c], x1 = vb[vro[1] + c];
                float x2 = vb[vro[2] + c], x3 = vb[vro[3] + c];
                float x4 = vb[vro[4] + c], x5 = vb[vro[5] + c];
                float x6 = vb[vro[6] + c], x7 = vb[vro[7] + c];
                U8 f;
                f.u[0] = pk_bf(x0, x1); f.u[1] = pk_bf(x2, x3);
                f.u[2] = pk_bf(x4, x5); f.u[3] = pk_bf(x6, x7);
                O[dt] = __builtin_amdgcn_mfma_f32_16x16x32_bf16(f.s, Pf, O[dt], 0, 0, 0);
            }
        }
    }

    if (active && ks > 0) {
        if (quad == 0) { sS[qt][ks][l16][0] = m; sS[qt][ks][l16][1] = l; }
        #pragma unroll
        for (int dt = 0; dt < 8; ++dt)
            *(floatx4*)&sC[qt][ks - 1][l16][dt * 16 + quad * 4] = O[dt];
    }
    __syncthreads();

    if (ks == 0) {
        const float* vm = vmean + b * DIM;
        float* ob = out + bo + (rowbase + l16) * DIM;
        if (active) {
            float mw[3], lw[3];
            float mstar = m;
            #pragma unroll
            for (int w = 0; w < 3; ++w) {
                mw[w] = sS[qt][w + 1][l16][0];
                lw[w] = sS[qt][w + 1][l16][1];
                mstar = fmaxf(mstar, mw[w]);
            }
            float s0 = __expf(m - mstar);
            float sw[3];
            float lstar = s0 * l;
            #pragma unroll
            for (int w = 0; w < 3; ++w) {
                sw[w] = __expf(mw[w] - mstar);
                lstar += sw[w] * lw[w];
            }
            float inv = 1.f / lstar;
            bool rowvalid = (rowbase + l16) < len;
            #pragma unroll
            for (int dt = 0; dt < 8; ++dt) {
                floatx4 acc = O[dt];
                #pragma unroll
                for (int r = 0; r < 4; ++r) acc[r] *= s0;
                #pragma unroll
                for (int w = 0; w < 3; ++w) {
                    floatx4 ow = *(const floatx4*)&sC[qt][w][l16][dt * 16 + quad * 4];
                    #pragma unroll
                    for (int r = 0; r < 4; ++r) acc[r] += sw[w] * ow[r];
                }
                float4 res;
                if (rowvalid) {
                    res = make_float4(acc[0] * inv, acc[1] * inv, acc[2] * inv, acc[3] * inv);
                } else {
                    res = *(const float4*)(vm + dt * 16 + quad * 4);
                }
                *(float4*)(ob + dt * 16 + quad * 4) = res;
            }
        } else {
            #pragma unroll
            for (int dt = 0; dt < 8; ++dt)
                *(float4*)(ob + dt * 16 + quad * 4) =
                    *(const float4*)(vm + dt * 16 + quad * 4);
        }
    }
}

extern "C" void kernel_launch(void* const* d_in, const int* in_sizes, int n_in,
                              void* d_out, int out_size, void* d_ws, size_t ws_size,
                              hipStream_t stream) {
    const float* q = (const float*)d_in[0];
    const float* k = (const float*)d_in[1];
    const float* v = (const float*)d_in[2];
    const int* lens = (const int*)d_in[3];
    float* out = (float*)d_out;

    if (ws_size >= (size_t)WS_NEEDED) {
        float* vpart = (float*)((char*)d_ws + OFF_VPART);
        float* vmean = (float*)((char*)d_ws + OFF_VMEAN);
        unsigned short* kw = (unsigned short*)((char*)d_ws + OFF_KW);
        unsigned short* vw = (unsigned short*)((char*)d_ws + OFF_VW);
        conv2<<<dim3(1024), dim3(256), 0, stream>>>(k, v, kw, vw, vpart);
        vmean2<<<dim3(8), dim3(128), 0, stream>>>(vpart, vmean);
        attn_fm<<<dim3(1024), dim3(256), 0, stream>>>(q, kw, vw, lens, vmean, out);
    } else {
        float* part = (float*)d_ws;
        float* vmean = part + 64 * DIM;
        vmean_partial<<<dim3(64), dim3(256), 0, stream>>>(v, part);
        vmean_combine<<<dim3(8), dim3(128), 0, stream>>>(part, vmean);
        attn_flash<<<dim3(512), dim3(512), 0, stream>>>(q, k, v, lens, vmean, out);
    }
}